// Round 1
// baseline (1741.783 us; speedup 1.0000x reference)
//
#include <hip/hip_runtime.h>
#include <cmath>

// Problem constants (match reference)
#define BB 512
#define TT 2048
#define IN 33
#define HH 64
#define OO 2

#define TPROJ 256   // t-steps per projection block

typedef float v2f __attribute__((ext_vector_type(2)));

__device__ __forceinline__ v2f pk_fma(v2f a, v2f b, v2f c) {
#if __has_builtin(__builtin_elementwise_fma)
    return __builtin_elementwise_fma(a, b, c);   // -> v_pk_fma_f32
#else
    v2f r; r.x = fmaf(a.x, b.x, c.x); r.y = fmaf(a.y, b.y, c.y); return r;
#endif
}

// tanh(x) = 1 - 2/(exp(2x)+1); exp(2x) = exp2(x * 2*log2(e)).
// v_exp_f32 + v_rcp_f32: ~1 ulp each; saturates to +/-1 correctly at +/-inf.
__device__ __forceinline__ float tanh_fast(float x) {
    float e = __builtin_amdgcn_exp2f(x * 2.8853900817779268f);
    float r = __builtin_amdgcn_rcpf(e + 1.0f);
    return fmaf(-2.0f, r, 1.0f);
}

// ---------------------------------------------------------------------------
// Kernel 1: input projection  xW[b,t,j] = sum_i x[b,t,i]*W_ih[j,i] + b_ih[j]
// One wave per (b, t-chunk). Lane j holds W_ih row j in registers; x row is
// wave-uniform (scalarizes to s_load). Output write is coalesced.
// __launch_bounds__(64,1): relax the register budget so wih[] stays VGPR-
// resident instead of being re-loaded every t step (VGPR sinking bug).
// ---------------------------------------------------------------------------
__global__ __launch_bounds__(64, 1) void proj_kernel(
    const float* __restrict__ x, const float* __restrict__ W_ih,
    const float* __restrict__ b_ih, float* __restrict__ hid)
{
    const int j  = threadIdx.x;        // 0..63 output channel
    const int b  = blockIdx.x;         // batch
    const int t0 = blockIdx.y * TPROJ; // t chunk start

    float wih[IN];
#pragma unroll
    for (int i = 0; i < IN; ++i) wih[i] = W_ih[j * IN + i];
    const float bias = b_ih[j];

    for (int t = t0; t < t0 + TPROJ; ++t) {
        const float* xr = x + ((size_t)b * TT + t) * IN;  // wave-uniform addr
        float acc = bias;
#pragma unroll
        for (int i = 0; i < IN; ++i) acc = fmaf(wih[i], xr[i], acc);
        hid[((size_t)b * TT + t) * HH + j] = acc;
    }
}

// ---------------------------------------------------------------------------
// Kernel 2: recurrence. One wave per batch. Lane j keeps W_hh row j as 32
// float2 pairs (64 VGPR, forced resident via __launch_bounds__(64,1)) and
// h[j] in a register. h broadcast via LDS: lane j writes sh[j], all lanes
// read back with uniform-address float4 loads (ds_read_b128 broadcast —
// no bank conflicts, no v_readlane->SGPR hazard chain). Inner product runs
// as v_pk_fma_f32 (packed f32, 2 FLOP/lane/instr).
// xW prefetched 4 steps ahead (double-buffered) to hide global latency.
// Reads xW from hid[] and overwrites the same location with h (in-place).
// ---------------------------------------------------------------------------
__global__ __launch_bounds__(64, 1) void rnn_kernel(
    const float* __restrict__ h0, const float* __restrict__ W_hh,
    const float* __restrict__ b_hh, float* __restrict__ hid)
{
    const int j = threadIdx.x;
    const int b = blockIdx.x;

    __shared__ __align__(16) float sh[HH];

    v2f w2[HH / 2];
#pragma unroll
    for (int k = 0; k < HH; k += 4) {
        const float4 v = *(const float4*)(W_hh + j * HH + k);
        w2[k / 2]     = (v2f){v.x, v.y};
        w2[k / 2 + 1] = (v2f){v.z, v.w};
    }
    const float bias = b_hh[j];
    float h = h0[b * HH + j];
    sh[j] = h;

    float* hrow = hid + (size_t)b * TT * HH + j;

    // prefetch first group (t = 0..3)
    float pf[8];
#pragma unroll
    for (int i = 0; i < 4; ++i) pf[i] = hrow[(size_t)i * HH];

    for (int tg = 0; tg < TT; tg += 4) {
        const int buf  = (tg >> 2) & 1;
        const int nbuf = buf ^ 1;
        // prefetch next group (clamped; duplicate loads at the tail are unused)
        const int tn = (tg + 4 < TT) ? (tg + 4) : (TT - 4);
#pragma unroll
        for (int i = 0; i < 4; ++i)
            pf[nbuf * 4 + i] = hrow[(size_t)(tn + i) * HH];

#pragma unroll
        for (int i = 0; i < 4; ++i) {
            // bias + xW folded into accumulator 0 (off the critical path)
            v2f a0 = (v2f){pf[buf * 4 + i] + bias, 0.f};
            v2f a1 = (v2f){0.f, 0.f}, a2 = a1, a3 = a1;
#pragma unroll
            for (int q = 0; q < 16; q += 2) {
                // uniform-address LDS reads -> hardware broadcast
                const float4 h4a = *(const float4*)(sh + 4 * q);
                const float4 h4b = *(const float4*)(sh + 4 * q + 4);
                a0 = pk_fma(w2[2 * q],     (v2f){h4a.x, h4a.y}, a0);
                a1 = pk_fma(w2[2 * q + 1], (v2f){h4a.z, h4a.w}, a1);
                a2 = pk_fma(w2[2 * q + 2], (v2f){h4b.x, h4b.y}, a2);
                a3 = pk_fma(w2[2 * q + 3], (v2f){h4b.z, h4b.w}, a3);
            }
            const v2f s = (a0 + a2) + (a1 + a3);   // v_pk_add_f32
            h = tanh_fast(s.x + s.y);
            sh[j] = h;                              // broadcast for next step
            hrow[(size_t)(tg + i) * HH] = h;
        }
    }
}

// ---------------------------------------------------------------------------
// Kernel 3: output projection  preds[b,t,o] = sum_j h[b,t,j]*W_ro[o,j] + b_ro[o]
// One thread per (b,t); W_ro is wave-uniform (scalarizable).
// ---------------------------------------------------------------------------
__global__ __launch_bounds__(256) void pred_kernel(
    const float* __restrict__ hid, const float* __restrict__ W_ro,
    const float* __restrict__ b_ro, float* __restrict__ preds)
{
    const size_t bt = (size_t)blockIdx.x * 256 + threadIdx.x; // 0..B*T-1
    const float4* hr = (const float4*)(hid + bt * HH);

    float p0 = 0.f, p1 = 0.f;
#pragma unroll
    for (int k = 0; k < 16; ++k) {
        const float4 h4 = hr[k];
        const float4 w0 = ((const float4*)W_ro)[k];
        const float4 w1 = ((const float4*)(W_ro + HH))[k];
        p0 = fmaf(w0.x, h4.x, fmaf(w0.y, h4.y, fmaf(w0.z, h4.z, fmaf(w0.w, h4.w, p0))));
        p1 = fmaf(w1.x, h4.x, fmaf(w1.y, h4.y, fmaf(w1.z, h4.z, fmaf(w1.w, h4.w, p1))));
    }
    float2 out;
    out.x = p0 + b_ro[0];
    out.y = p1 + b_ro[1];
    ((float2*)(preds))[bt] = out;
}

// ---------------------------------------------------------------------------
extern "C" void kernel_launch(void* const* d_in, const int* in_sizes, int n_in,
                              void* d_out, int out_size, void* d_ws, size_t ws_size,
                              hipStream_t stream)
{
    const float* x    = (const float*)d_in[0];
    const float* h0   = (const float*)d_in[1];
    const float* W_ih = (const float*)d_in[2];
    const float* W_hh = (const float*)d_in[3];
    const float* b_ih = (const float*)d_in[4];
    const float* b_hh = (const float*)d_in[5];
    const float* W_ro = (const float*)d_in[6];
    const float* b_ro = (const float*)d_in[7];

    float* out   = (float*)d_out;
    float* preds = out;                         // [B,T,O]
    float* hid   = out + (size_t)BB * TT * OO;  // [B,T,H] (also xW scratch)

    // 1) xW into hidden region (scratch until recurrence overwrites in place)
    proj_kernel<<<dim3(BB, TT / TPROJ), 64, 0, stream>>>(x, W_ih, b_ih, hid);

    // 2) recurrence, in place on hid (one wave per batch)
    rnn_kernel<<<BB, 64, 0, stream>>>(h0, W_hh, b_hh, hid);

    // 3) predictions
    pred_kernel<<<(BB * TT) / 256, 256, 0, stream>>>(hid, W_ro, b_ro, preds);
}

// Round 2
// 1696.638 us; speedup vs baseline: 1.0266x; 1.0266x over previous
//
#include <hip/hip_runtime.h>
#include <cmath>

// Problem constants (match reference)
#define BB 512
#define TT 2048
#define IN 33
#define HH 64
#define OO 2

#define TB 64      // bt-rows per proj block
#define G  8       // rnn time-steps per prefetch group

__device__ __forceinline__ float readlane_f(float v, int lane) {
    return __int_as_float(__builtin_amdgcn_readlane(__float_as_int(v), lane));
}

// tanh(x) = 1 - 2/(exp(2x)+1); exp(2x) = exp2(x * 2*log2(e)).
// v_exp_f32 + v_rcp_f32: ~1 ulp each; saturates to +/-1 correctly at +/-inf.
__device__ __forceinline__ float tanh_fast(float x) {
    float e = __builtin_amdgcn_exp2f(x * 2.8853900817779268f);
    float r = __builtin_amdgcn_rcpf(e + 1.0f);
    return fmaf(-2.0f, r, 1.0f);
}

// ---------------------------------------------------------------------------
// Kernel 1: input projection  xW[b,t,j] = sum_i x[b,t,i]*W_ih[j,i] + b_ih[j]
// Tiled: 256-thread block stages TB=64 contiguous (b,t) rows of x into LDS
// (coalesced, 8448 B), then each of the 4 waves computes 16 rows. Lane j
// holds W_ih row j in registers (asm-pinned so they are NOT re-loaded per
// row); x elements come from LDS with wave-uniform addresses (broadcast,
// conflict-free). Store is lane=channel -> 256 B coalesced per wave-row.
// ---------------------------------------------------------------------------
__global__ __launch_bounds__(256, 2) void proj_kernel(
    const float* __restrict__ x, const float* __restrict__ W_ih,
    const float* __restrict__ b_ih, float* __restrict__ hid)
{
    __shared__ float xs[TB * IN];            // 64 x 33 floats
    const int tid = threadIdx.x;
    const size_t row0 = (size_t)blockIdx.x * TB;   // first bt row of this block

    // cooperative coalesced stage: 64 rows x 33 floats are contiguous in x
    const float* xsrc = x + row0 * IN;
    for (int idx = tid; idx < TB * IN; idx += 256)
        xs[idx] = xsrc[idx];

    const int j  = tid & 63;    // output channel (lane)
    const int wv = tid >> 6;    // wave id 0..3

    float wih[IN];
#pragma unroll
    for (int i = 0; i < IN; ++i) wih[i] = W_ih[j * IN + i];
#pragma unroll
    for (int i = 0; i < IN; ++i) asm volatile("" : "+v"(wih[i]));  // pin in VGPRs
    const float bias = b_ih[j];

    __syncthreads();

    // wave wv handles rows wv, wv+4, ..., wv+60 (16 rows, wave-uniform)
#pragma unroll
    for (int m = 0; m < 16; ++m) {
        const int r = wv + 4 * m;
        const float* xr = xs + r * IN;       // wave-uniform LDS address
        float acc = bias;
#pragma unroll
        for (int i = 0; i < IN; ++i) acc = fmaf(wih[i], xr[i], acc);
        hid[(row0 + r) * HH + j] = acc;
    }
}

// ---------------------------------------------------------------------------
// Kernel 2: recurrence. One wave per batch. Lane j keeps W_hh row j in 64
// VGPRs -- asm-pinned so the allocator cannot sink the loads back into the
// time loop (rounds 0/1 showed VGPR_Count 44/64 => weights were re-loaded
// from L1 every iteration, stalling the serial chain). h[k] broadcast via
// v_readlane feeding the SGPR operand of v_fmac (2 instr per MAC, no LDS
// round-trip). xW prefetched G=8 steps ahead (double-buffered) to cover
// ~900 cy HBM/L3 latency. In-place: reads xW from hid[], overwrites with h.
// ---------------------------------------------------------------------------
__global__ __launch_bounds__(64, 1) void rnn_kernel(
    const float* __restrict__ h0, const float* __restrict__ W_hh,
    const float* __restrict__ b_hh, float* __restrict__ hid)
{
    const int j = threadIdx.x;
    const int b = blockIdx.x;

    float w[HH];
#pragma unroll
    for (int k = 0; k < HH; k += 4) {
        const float4 v = *(const float4*)(W_hh + j * HH + k);
        w[k] = v.x; w[k + 1] = v.y; w[k + 2] = v.z; w[k + 3] = v.w;
    }
#pragma unroll
    for (int k = 0; k < HH; ++k) asm volatile("" : "+v"(w[k]));    // pin in VGPRs

    const float bias = b_hh[j];
    float h = h0[b * HH + j];

    float* hrow = hid + (size_t)b * TT * HH + j;

    // prefetch first group (t = 0..G-1)
    float pf[2 * G];
#pragma unroll
    for (int i = 0; i < G; ++i) pf[i] = hrow[(size_t)i * HH];

    for (int tg = 0; tg < TT; tg += G) {
        const int buf  = (tg / G) & 1;
        const int nbuf = buf ^ 1;
        // prefetch next group (clamped; duplicate loads at the tail are unused)
        const int tn = (tg + G < TT) ? (tg + G) : (TT - G);
#pragma unroll
        for (int i = 0; i < G; ++i)
            pf[nbuf * G + i] = hrow[(size_t)(tn + i) * HH];

#pragma unroll
        for (int i = 0; i < G; ++i) {
            float a0 = 0.f, a1 = 0.f, a2 = 0.f, a3 = 0.f;
#pragma unroll
            for (int k = 0; k < HH; k += 4) {
                a0 = fmaf(w[k + 0], readlane_f(h, k + 0), a0);
                a1 = fmaf(w[k + 1], readlane_f(h, k + 1), a1);
                a2 = fmaf(w[k + 2], readlane_f(h, k + 2), a2);
                a3 = fmaf(w[k + 3], readlane_f(h, k + 3), a3);
            }
            const float z = pf[buf * G + i] + bias + ((a0 + a1) + (a2 + a3));
            h = tanh_fast(z);
            hrow[(size_t)(tg + i) * HH] = h;
        }
    }
}

// ---------------------------------------------------------------------------
// Kernel 3: output projection  preds[b,t,o] = sum_j h[b,t,j]*W_ro[o,j] + b_ro[o]
// One thread per (b,t); W_ro is wave-uniform (scalarizable).
// ---------------------------------------------------------------------------
__global__ __launch_bounds__(256) void pred_kernel(
    const float* __restrict__ hid, const float* __restrict__ W_ro,
    const float* __restrict__ b_ro, float* __restrict__ preds)
{
    const size_t bt = (size_t)blockIdx.x * 256 + threadIdx.x; // 0..B*T-1
    const float4* hr = (const float4*)(hid + bt * HH);

    float p0 = 0.f, p1 = 0.f;
#pragma unroll
    for (int k = 0; k < 16; ++k) {
        const float4 h4 = hr[k];
        const float4 w0 = ((const float4*)W_ro)[k];
        const float4 w1 = ((const float4*)(W_ro + HH))[k];
        p0 = fmaf(w0.x, h4.x, fmaf(w0.y, h4.y, fmaf(w0.z, h4.z, fmaf(w0.w, h4.w, p0))));
        p1 = fmaf(w1.x, h4.x, fmaf(w1.y, h4.y, fmaf(w1.z, h4.z, fmaf(w1.w, h4.w, p1))));
    }
    float2 out;
    out.x = p0 + b_ro[0];
    out.y = p1 + b_ro[1];
    ((float2*)(preds))[bt] = out;
}

// ---------------------------------------------------------------------------
extern "C" void kernel_launch(void* const* d_in, const int* in_sizes, int n_in,
                              void* d_out, int out_size, void* d_ws, size_t ws_size,
                              hipStream_t stream)
{
    const float* x    = (const float*)d_in[0];
    const float* h0   = (const float*)d_in[1];
    const float* W_ih = (const float*)d_in[2];
    const float* W_hh = (const float*)d_in[3];
    const float* b_ih = (const float*)d_in[4];
    const float* b_hh = (const float*)d_in[5];
    const float* W_ro = (const float*)d_in[6];
    const float* b_ro = (const float*)d_in[7];

    float* out   = (float*)d_out;
    float* preds = out;                         // [B,T,O]
    float* hid   = out + (size_t)BB * TT * OO;  // [B,T,H] (also xW scratch)

    // 1) xW into hidden region (scratch until recurrence overwrites in place)
    proj_kernel<<<(BB * TT) / TB, 256, 0, stream>>>(x, W_ih, b_ih, hid);

    // 2) recurrence, in place on hid (one wave per batch)
    rnn_kernel<<<BB, 64, 0, stream>>>(h0, W_hh, b_hh, hid);

    // 3) predictions
    pred_kernel<<<(BB * TT) / 256, 256, 0, stream>>>(hid, W_ro, b_ro, preds);
}

// Round 4
// 998.677 us; speedup vs baseline: 1.7441x; 1.6989x over previous
//
#include <hip/hip_runtime.h>
#include <cmath>

// Problem constants (match reference)
#define BB 512
#define TT 2048
#define IN 33
#define HH 64
#define OO 2

#define TB 64      // bt-rows per proj block
#define G  8       // rnn time-steps per prefetch group

typedef float v4f __attribute__((ext_vector_type(4)));

__device__ __forceinline__ float readlane_f(float v, int lane) {
    return __int_as_float(__builtin_amdgcn_readlane(__float_as_int(v), lane));
}

// tanh(x) = 1 - 2/(exp(2x)+1); exp(2x) = exp2(x * 2*log2(e)).
// v_exp_f32 + v_rcp_f32: ~1 ulp each; saturates to +/-1 correctly at +/-inf.
__device__ __forceinline__ float tanh_fast(float x) {
    float e = __builtin_amdgcn_exp2f(x * 2.8853900817779268f);
    float r = __builtin_amdgcn_rcpf(e + 1.0f);
    return fmaf(-2.0f, r, 1.0f);
}

// ---------------------------------------------------------------------------
// Kernel 1: input projection  xW[b,t,j] = sum_i x[b,t,i]*W_ih[j,i] + b_ih[j]
// 256-thread block stages TB=64 contiguous (b,t) rows of x into LDS
// (coalesced), then each of the 4 waves computes 16 rows: lane j holds W_ih
// row j (compiler-managed; this kernel has TLP to hide any L1 re-loads),
// x elements come from LDS with wave-uniform addresses (broadcast, conflict
// free). Store is lane=channel -> coalesced. NO asm pins (round-2 lesson).
// ---------------------------------------------------------------------------
__global__ __launch_bounds__(256, 2) void proj_kernel(
    const float* __restrict__ x, const float* __restrict__ W_ih,
    const float* __restrict__ b_ih, float* __restrict__ hid)
{
    __shared__ float xs[TB * IN];            // 64 x 33 floats
    const int tid = threadIdx.x;
    const size_t row0 = (size_t)blockIdx.x * TB;   // first bt row of this block

    // cooperative coalesced stage: 64 rows x 33 floats are contiguous in x
    const float* xsrc = x + row0 * IN;
    for (int idx = tid; idx < TB * IN; idx += 256)
        xs[idx] = xsrc[idx];

    const int j  = tid & 63;    // output channel (lane)
    const int wv = tid >> 6;    // wave id 0..3

    float wih[IN];
#pragma unroll
    for (int i = 0; i < IN; ++i) wih[i] = W_ih[j * IN + i];
    const float bias = b_ih[j];

    __syncthreads();

    // wave wv handles rows wv, wv+4, ..., wv+60 (16 rows, wave-uniform)
#pragma unroll
    for (int m = 0; m < 16; ++m) {
        const int r = wv + 4 * m;
        const float* xr = xs + r * IN;       // wave-uniform LDS address
        float acc = bias;
#pragma unroll
        for (int i = 0; i < IN; ++i) acc = fmaf(wih[i], xr[i], acc);
        hid[(row0 + r) * HH + j] = acc;
    }
}

// ---------------------------------------------------------------------------
// Kernel 2: recurrence. One wave per batch; lane j computes h[j].
// Weight residency: load W_hh row j into wv[16] (v4f) ONCE, then pass all 16
// through a single asm "+v" pin. The asm becomes the defining instruction of
// the values => the compiler CANNOT rematerialize the loads inside the time
// loop (rounds 0/1 bug), and with ~100 live VGPRs vs the 512 budget of
// __launch_bounds__(64,1) it keeps them resident (round 2's 64 separate
// per-scalar pins caused scratch; ONE asm does not).
// h[k] broadcast via v_readlane feeding v_fmac's SGPR operand (LDS broadcast
// measured slower in round 1). xW prefetched G=8 steps ahead into named
// ping-pong buffers (all indices static), issued a full group (~2400 cy)
// before first use so the in-order vmcnt FIFO never stalls the chain.
// In-place: reads xW from hid[], overwrites with h.
// ---------------------------------------------------------------------------
__global__ __launch_bounds__(64, 1) void rnn_kernel(
    const float* __restrict__ h0, const float* __restrict__ W_hh,
    const float* __restrict__ b_hh, float* __restrict__ hid)
{
    const int j = threadIdx.x;
    const int b = blockIdx.x;

    // --- load W_hh row j and pin it in VGPRs (one-time) ---
    v4f wv[16];
    const v4f* wrow = (const v4f*)(W_hh + (size_t)j * HH);
#pragma unroll
    for (int c = 0; c < 16; ++c) wv[c] = wrow[c];
    // single pin: defs become asm outputs -> no remat, no per-step reloads
    asm volatile(""
        : "+v"(wv[0]), "+v"(wv[1]), "+v"(wv[2]),  "+v"(wv[3]),
          "+v"(wv[4]), "+v"(wv[5]), "+v"(wv[6]),  "+v"(wv[7]),
          "+v"(wv[8]), "+v"(wv[9]), "+v"(wv[10]), "+v"(wv[11]),
          "+v"(wv[12]), "+v"(wv[13]), "+v"(wv[14]), "+v"(wv[15]));

    const float bias = b_hh[j];
    float h = h0[b * HH + j];

    float* hrow = hid + (size_t)b * TT * HH + j;

    float pfA[G], pfB[G];
#pragma unroll
    for (int i = 0; i < G; ++i) pfA[i] = hrow[(size_t)i * HH];

#define RNN_STEP(PF, T)                                                        \
    {                                                                          \
        float a0 = (PF), a1 = bias, a2 = 0.f, a3 = 0.f;                        \
        _Pragma("unroll")                                                      \
        for (int c = 0; c < 16; ++c) {                                         \
            a0 = fmaf(wv[c].x, readlane_f(h, 4 * c + 0), a0);                  \
            a1 = fmaf(wv[c].y, readlane_f(h, 4 * c + 1), a1);                  \
            a2 = fmaf(wv[c].z, readlane_f(h, 4 * c + 2), a2);                  \
            a3 = fmaf(wv[c].w, readlane_f(h, 4 * c + 3), a3);                  \
        }                                                                      \
        h = tanh_fast((a0 + a1) + (a2 + a3));                                  \
        hrow[(size_t)(T) * HH] = h;                                            \
    }

    for (int tg = 0; tg < TT; tg += 2 * G) {
        // prefetch group tg+G into pfB before computing on pfA
#pragma unroll
        for (int i = 0; i < G; ++i) pfB[i] = hrow[(size_t)(tg + G + i) * HH];

#pragma unroll
        for (int i = 0; i < G; ++i) RNN_STEP(pfA[i], tg + i);

        // prefetch group tg+2G into pfA (clamped; tail duplicates unused)
        const int tn = (tg + 2 * G < TT) ? (tg + 2 * G) : (TT - G);
#pragma unroll
        for (int i = 0; i < G; ++i) pfA[i] = hrow[(size_t)(tn + i) * HH];

#pragma unroll
        for (int i = 0; i < G; ++i) RNN_STEP(pfB[i], tg + G + i);
    }
#undef RNN_STEP
}

// ---------------------------------------------------------------------------
// Kernel 3: output projection  preds[b,t,o] = sum_j h[b,t,j]*W_ro[o,j] + b_ro[o]
// One thread per (b,t); W_ro is wave-uniform (scalarizable). Each 64B line
// of hid is consumed fully across 4 consecutive k-iterations -> L1-friendly.
// ---------------------------------------------------------------------------
__global__ __launch_bounds__(256) void pred_kernel(
    const float* __restrict__ hid, const float* __restrict__ W_ro,
    const float* __restrict__ b_ro, float* __restrict__ preds)
{
    const size_t bt = (size_t)blockIdx.x * 256 + threadIdx.x; // 0..B*T-1
    const float4* hr = (const float4*)(hid + bt * HH);

    float p0 = 0.f, p1 = 0.f;
#pragma unroll
    for (int k = 0; k < 16; ++k) {
        const float4 h4 = hr[k];
        const float4 w0 = ((const float4*)W_ro)[k];
        const float4 w1 = ((const float4*)(W_ro + HH))[k];
        p0 = fmaf(w0.x, h4.x, fmaf(w0.y, h4.y, fmaf(w0.z, h4.z, fmaf(w0.w, h4.w, p0))));
        p1 = fmaf(w1.x, h4.x, fmaf(w1.y, h4.y, fmaf(w1.z, h4.z, fmaf(w1.w, h4.w, p1))));
    }
    float2 out;
    out.x = p0 + b_ro[0];
    out.y = p1 + b_ro[1];
    ((float2*)(preds))[bt] = out;
}

// ---------------------------------------------------------------------------
extern "C" void kernel_launch(void* const* d_in, const int* in_sizes, int n_in,
                              void* d_out, int out_size, void* d_ws, size_t ws_size,
                              hipStream_t stream)
{
    const float* x    = (const float*)d_in[0];
    const float* h0   = (const float*)d_in[1];
    const float* W_ih = (const float*)d_in[2];
    const float* W_hh = (const float*)d_in[3];
    const float* b_ih = (const float*)d_in[4];
    const float* b_hh = (const float*)d_in[5];
    const float* W_ro = (const float*)d_in[6];
    const float* b_ro = (const float*)d_in[7];

    float* out   = (float*)d_out;
    float* preds = out;                         // [B,T,O]
    float* hid   = out + (size_t)BB * TT * OO;  // [B,T,H] (also xW scratch)

    // 1) xW into hidden region (scratch until recurrence overwrites in place)
    proj_kernel<<<(BB * TT) / TB, 256, 0, stream>>>(x, W_ih, b_ih, hid);

    // 2) recurrence, in place on hid (one wave per batch)
    rnn_kernel<<<BB, 64, 0, stream>>>(h0, W_hh, b_hh, hid);

    // 3) predictions
    pred_kernel<<<(BB * TT) / 256, 256, 0, stream>>>(hid, W_ro, b_ro, preds);
}